// Round 4
// baseline (203.793 us; speedup 1.0000x reference)
//
#include <hip/hip_runtime.h>
#include <stdint.h>

typedef short bf16x8 __attribute__((ext_vector_type(8)));
typedef float f32x4 __attribute__((ext_vector_type(4)));
typedef unsigned short ushort_t;
typedef ushort_t ushort8 __attribute__((ext_vector_type(8)));

#define TOKENS 131072
#define DMODEL 128
#define DIN 160
#define DHID 512
#define NEXP 8
#define BEH 32
#define CAP 24576
#define MT 128
#define TILES (CAP / MT)   /* 192 */

// workspace layout (bytes)
#define OFF_COUNTS 0
#define OFF_LISTS  1024
#define OFF_WIP    (OFF_LISTS + NEXP*CAP*4)
#define OFF_WOP    (OFF_WIP + 8*32*5*64*8*2)

#define SCATTER_BLOCKS (TOKENS / 256)                /* 512 */
#define NWI (8*32*5*64)                              /* 81920 */
#define NWO (8*8*16*64)                              /* 65536 */
#define PACK_BLOCKS ((NWI + NWO + 255) / 256)        /* 576 */

__device__ __forceinline__ ushort_t f2b(float f) {
    union { float f; uint32_t u; } x; x.f = f;
    uint32_t r = x.u + 0x7FFF + ((x.u >> 16) & 1);   // RNE
    return (ushort_t)(r >> 16);
}

// pack two f32 -> two bf16 (round-half-up)
__device__ __forceinline__ uint32_t pk2(float lo, float hi) {
    uint32_t a = __float_as_uint(lo) + 0x8000u;
    uint32_t b = __float_as_uint(hi) + 0x8000u;
    return (a >> 16) | (b & 0xFFFF0000u);
}

// ---------------- Phase A+B fused: scatter tokens + pack weights ----------------
__global__ __launch_bounds__(256) void prep_kernel(
    const int* __restrict__ pos, int* __restrict__ counts, int* __restrict__ lists,
    const float* __restrict__ Wi, const float* __restrict__ Wo,
    ushort_t* __restrict__ wiP, ushort_t* __restrict__ woP)
{
    __shared__ int lcnt[NEXP];
    __shared__ int lbase[NEXP];
    int tid = threadIdx.x;
    if (blockIdx.x < SCATTER_BLOCKS) {
        if (tid < NEXP) lcnt[tid] = 0;
        __syncthreads();
        int t = blockIdx.x * 256 + tid;
        int e = pos[t];
        int slot = atomicAdd(&lcnt[e], 1);
        __syncthreads();
        if (tid < NEXP) lbase[tid] = atomicAdd(&counts[tid], lcnt[tid]);
        __syncthreads();
        int p = lbase[e] + slot;
        if (p < CAP) lists[e * CAP + p] = t;
        return;
    }
    int idx = (blockIdx.x - SCATTER_BLOCKS) * 256 + tid;
    // fragment layout (operand-symmetric): lane L holds W[k=(L>>4)*8+j][d16=L&15]
    if (idx < NWI) {
        int L = idx & 63; int r = idx >> 6;
        int s = r % 5; r /= 5;
        int t1 = r & 31; int e = r >> 5;
        int n = t1 * 16 + (L & 15);
        int kb = s * 32 + ((L >> 4) & 3) * 8;
        ushort8 o;
        #pragma unroll
        for (int j = 0; j < 8; ++j)
            o[j] = f2b(Wi[((size_t)e * DIN + kb + j) * DHID + n]);
        *(ushort8*)(wiP + (size_t)idx * 8) = o;
    } else {
        int i2 = idx - NWI;
        if (i2 >= NWO) return;
        int L = i2 & 63; int r = i2 >> 6;
        int ks = r & 15; r >>= 4;
        int t2 = r & 7; int e = r >> 3;
        int n = t2 * 16 + (L & 15);
        int kb = ks * 32 + ((L >> 4) & 3) * 8;
        ushort8 o;
        #pragma unroll
        for (int j = 0; j < 8; ++j)
            o[j] = f2b(Wo[((size_t)e * DHID + kb + j) * DMODEL + n]);
        *(ushort8*)(woP + (size_t)i2 * 8) = o;
    }
}

// x = concat(hidden[t], emb[bi]); 8 consecutive floats at col c0 (8-aligned)
__device__ __forceinline__ bf16x8 load_x8(const float* __restrict__ hidden,
                                          const float* __restrict__ emb,
                                          int t, int bi, int c0) {
    if (t < 0) return (bf16x8)0;
    const float* src = (c0 < DMODEL) ? (hidden + (size_t)t * DMODEL + c0)
                                     : (emb + (size_t)bi * BEH + (c0 - DMODEL));
    f32x4 p0 = *(const f32x4*)src;
    f32x4 p1 = *(const f32x4*)(src + 4);
    uint32_t d0 = pk2(p0[0], p0[1]), d1 = pk2(p0[2], p0[3]);
    uint32_t d2 = pk2(p1[0], p1[1]), d3 = pk2(p1[2], p1[3]);
    return __builtin_bit_cast(bf16x8, (uint4){d0, d1, d2, d3});
}

// ---------------- Phase C: per-expert fused MLP (barrier-free streaming) ----------------
// block = 128 tokens, 4 waves, wave owns 32 tokens (2 token-tiles).
// NO LDS, NO __syncthreads: weight fragments are streamed straight from the
// packed global buffers (L1/L2-resident, 2.3 MB total; all waves of a block
// read identical 1 KB coalesced granules -> L1 broadcast). Every wave is a
// fully independent pipeline of {coalesced loads + MFMA + shuffles}.
__global__ __launch_bounds__(256, 2) void expert_gemm(
    const float* __restrict__ hidden, const int* __restrict__ bindex,
    const int* __restrict__ lists, const int* __restrict__ counts,
    const ushort_t* __restrict__ wiP, const ushort_t* __restrict__ woP,
    const float* __restrict__ emb, float* __restrict__ out)
{
    int e = blockIdx.y;
    int tile = blockIdx.x;
    int count = counts[e]; if (count > CAP) count = CAP;
    int base = tile * MT;
    if (base >= count) return;
    int mvalid = count - base; if (mvalid > MT) mvalid = MT;

    int tid = threadIdx.x;
    int lane = tid & 63;
    int w = tid >> 6;
    int l15 = lane & 15;
    int quad = lane >> 4;

    const int* listE = lists + (size_t)e * CAP + base;
    const ushort_t* wiPe = wiP + (size_t)e * 32 * 5 * 64 * 8;   // [t1 32][s 5][64][8]
    const ushort_t* woPe = woP + (size_t)e * 8 * 16 * 64 * 8;   // [n 8][ks 16][64][8]

    // ---- x B-fragments in registers: lane holds x[k=s*32+quad*8+j][tok=base+tt*16+l15]
    bf16x8 xf[2][5];
    int tok[2], bi[2];
    #pragma unroll
    for (int tt = 0; tt < 2; ++tt) {
        int row = w * 32 + tt * 16 + l15;
        tok[tt] = -1; bi[tt] = 0;
        if (row < mvalid) { tok[tt] = listE[row]; bi[tt] = bindex[tok[tt]]; }
    }
    #pragma unroll
    for (int s = 0; s < 5; ++s) {
        int c0 = s * 32 + quad * 8;
        xf[0][s] = load_x8(hidden, emb, tok[0], bi[0], c0);
        xf[1][s] = load_x8(hidden, emb, tok[1], bi[1], c0);
    }

    int srcA = (quad & 1) * 32 + l15;   // shuffle sources for h layout transform
    int srcB = srcA + 16;
    int selM1 = quad >> 1;

    f32x4 yacc[2][8] = {};

    #pragma unroll 2
    for (int step = 0; step < 16; ++step) {     // 16 K-steps of 32 hidden units
        // per-step fragment base pointers (global, L1/L2-hot)
        const ushort_t* wiS = wiPe + (size_t)step * 5120;   // tiles 2*step,2*step+1
        const ushort_t* woS = woPe + (size_t)step * 512;    // + n*8192 per n-tile

        // GEMM1^T: hT[32 hid x 32 tok] = Wi-tiles @ x
        f32x4 hacc[2][2] = {};
        #pragma unroll
        for (int s = 0; s < 5; ++s) {
            bf16x8 a0 = *(const bf16x8*)&wiS[(0 * 5 + s) * 512 + lane * 8];
            bf16x8 a1 = *(const bf16x8*)&wiS[(1 * 5 + s) * 512 + lane * 8];
            #pragma unroll
            for (int tt = 0; tt < 2; ++tt) {
                hacc[0][tt] = __builtin_amdgcn_mfma_f32_16x16x32_bf16(a0, xf[tt][s], hacc[0][tt], 0, 0, 0);
                hacc[1][tt] = __builtin_amdgcn_mfma_f32_16x16x32_bf16(a1, xf[tt][s], hacc[1][tt], 0, 0, 0);
            }
        }
        // issue GEMM2 B-frag loads EARLY (latency hides under shuffle/pack below)
        bf16x8 bfr[8];
        #pragma unroll
        for (int n = 0; n < 8; ++n)
            bfr[n] = *(const bf16x8*)&woS[(size_t)n * 8192 + lane * 8];

        // relu + pack + shuffle-transpose -> GEMM2 A-frags (both token-tiles)
        bf16x8 afrag[2];
        #pragma unroll
        for (int tt = 0; tt < 2; ++tt) {
            f32x4 h0 = hacc[0][tt], h1 = hacc[1][tt];
            #pragma unroll
            for (int r = 0; r < 4; ++r) {
                h0[r] = h0[r] > 0.f ? h0[r] : 0.f;
                h1[r] = h1[r] > 0.f ? h1[r] : 0.f;
            }
            uint32_t p00 = pk2(h0[0], h0[1]), p01 = pk2(h0[2], h0[3]);
            uint32_t p10 = pk2(h1[0], h1[1]), p11 = pk2(h1[2], h1[3]);
            uint32_t a00 = (uint32_t)__shfl((int)p00, srcA);
            uint32_t a01 = (uint32_t)__shfl((int)p01, srcA);
            uint32_t a02 = (uint32_t)__shfl((int)p00, srcB);
            uint32_t a03 = (uint32_t)__shfl((int)p01, srcB);
            uint32_t a10 = (uint32_t)__shfl((int)p10, srcA);
            uint32_t a11 = (uint32_t)__shfl((int)p11, srcA);
            uint32_t a12 = (uint32_t)__shfl((int)p10, srcB);
            uint32_t a13 = (uint32_t)__shfl((int)p11, srcB);
            uint4 dv = { selM1 ? a10 : a00, selM1 ? a11 : a01,
                         selM1 ? a12 : a02, selM1 ? a13 : a03 };
            afrag[tt] = __builtin_bit_cast(bf16x8, dv);
        }
        // GEMM2: 2 MFMAs per b-frag
        #pragma unroll
        for (int n = 0; n < 8; ++n) {
            yacc[0][n] = __builtin_amdgcn_mfma_f32_16x16x32_bf16(afrag[0], bfr[n], yacc[0][n], 0, 0, 0);
            yacc[1][n] = __builtin_amdgcn_mfma_f32_16x16x32_bf16(afrag[1], bfr[n], yacc[1][n], 0, 0, 0);
        }
    }

    // epilogue: yacc C-layout -> out[token][dmodel]
    #pragma unroll
    for (int tt = 0; tt < 2; ++tt)
        #pragma unroll
        for (int r = 0; r < 4; ++r) {
            int row = w * 32 + tt * 16 + quad * 4 + r;
            if (row < mvalid) {
                int t = listE[row];
                float* dst = out + (size_t)t * DMODEL + l15;
                #pragma unroll
                for (int n = 0; n < 8; ++n)
                    dst[n * 16] = yacc[tt][n][r];
            }
        }
}

extern "C" void kernel_launch(void* const* d_in, const int* in_sizes, int n_in,
                              void* d_out, int out_size, void* d_ws, size_t ws_size,
                              hipStream_t stream) {
    const float* hidden = (const float*)d_in[0];
    const int*   pos    = (const int*)d_in[1];
    const int*   beh    = (const int*)d_in[2];
    const float* Wi     = (const float*)d_in[3];
    const float* Wo     = (const float*)d_in[4];
    const float* emb    = (const float*)d_in[5];

    char* ws = (char*)d_ws;
    int* counts   = (int*)(ws + OFF_COUNTS);
    int* lists    = (int*)(ws + OFF_LISTS);
    ushort_t* wiP = (ushort_t*)(ws + OFF_WIP);
    ushort_t* woP = (ushort_t*)(ws + OFF_WOP);

    hipMemsetAsync(counts, 0, NEXP * sizeof(int), stream);
    prep_kernel<<<SCATTER_BLOCKS + PACK_BLOCKS, 256, 0, stream>>>(pos, counts, lists, Wi, Wo, wiP, woP);
    expert_gemm<<<dim3(TILES, NEXP), 256, 0, stream>>>(
        hidden, beh, lists, counts, wiP, woP, emb, (float*)d_out);
}

// Round 5
// 93.911 us; speedup vs baseline: 2.1701x; 2.1701x over previous
//
#include <hip/hip_runtime.h>
#include <stdint.h>

typedef short bf16x8 __attribute__((ext_vector_type(8)));
typedef float f32x4 __attribute__((ext_vector_type(4)));
typedef unsigned short ushort_t;
typedef ushort_t ushort8 __attribute__((ext_vector_type(8)));

#define TOKENS 131072
#define DMODEL 128
#define DIN 160
#define DHID 512
#define NEXP 8
#define BEH 32
#define CAP 24576
#define MT 128
#define TILES (CAP / MT)   /* 192 */

// workspace layout (bytes)
#define OFF_COUNTS 0
#define OFF_LISTS  1024
#define OFF_WIP    (OFF_LISTS + NEXP*CAP*4)
#define OFF_WOP    (OFF_WIP + 8*32*5*64*8*2)

#define SCATTER_BLOCKS (TOKENS / 256)                /* 512 */
#define NWI (8*32*5*64)                              /* 81920 */
#define NWO (8*8*16*64)                              /* 65536 */
#define PACK_BLOCKS ((NWI + NWO + 255) / 256)        /* 576 */

// super-step = 64 hidden units (2 of the old 32-unit steps).
// buffer: Wi 10240 shorts (20 KB: sub0 5120 + sub1 5120) + Wo 8192 shorts
// (16 KB: [n 8][kl 2][64][8]) = 18432 shorts = 36 KB. dbuf -> 72 KB LDS.
#define SUPER_SHORTS 18432
#define WO_BASE 10240

typedef const __attribute__((address_space(1))) uint32_t* gu32p;
typedef __attribute__((address_space(3))) uint32_t* lu32p;

__device__ __forceinline__ ushort_t f2b(float f) {
    union { float f; uint32_t u; } x; x.f = f;
    uint32_t r = x.u + 0x7FFF + ((x.u >> 16) & 1);   // RNE
    return (ushort_t)(r >> 16);
}

// pack two f32 -> two bf16 (round-half-up)
__device__ __forceinline__ uint32_t pk2(float lo, float hi) {
    uint32_t a = __float_as_uint(lo) + 0x8000u;
    uint32_t b = __float_as_uint(hi) + 0x8000u;
    return (a >> 16) | (b & 0xFFFF0000u);
}

// ---------------- Phase A+B fused: scatter tokens + pack weights ----------------
__global__ __launch_bounds__(256) void prep_kernel(
    const int* __restrict__ pos, int* __restrict__ counts, int* __restrict__ lists,
    const float* __restrict__ Wi, const float* __restrict__ Wo,
    ushort_t* __restrict__ wiP, ushort_t* __restrict__ woP)
{
    __shared__ int lcnt[NEXP];
    __shared__ int lbase[NEXP];
    int tid = threadIdx.x;
    if (blockIdx.x < SCATTER_BLOCKS) {
        if (tid < NEXP) lcnt[tid] = 0;
        __syncthreads();
        int t = blockIdx.x * 256 + tid;
        int e = pos[t];
        int slot = atomicAdd(&lcnt[e], 1);
        __syncthreads();
        if (tid < NEXP) lbase[tid] = atomicAdd(&counts[tid], lcnt[tid]);
        __syncthreads();
        int p = lbase[e] + slot;
        if (p < CAP) lists[e * CAP + p] = t;
        return;
    }
    int idx = (blockIdx.x - SCATTER_BLOCKS) * 256 + tid;
    // fragment layout (operand-symmetric): lane L holds W[k=(L>>4)*8+j][d16=L&15]
    if (idx < NWI) {
        int L = idx & 63; int r = idx >> 6;
        int s = r % 5; r /= 5;
        int t1 = r & 31; int e = r >> 5;
        int n = t1 * 16 + (L & 15);
        int kb = s * 32 + ((L >> 4) & 3) * 8;
        ushort8 o;
        #pragma unroll
        for (int j = 0; j < 8; ++j)
            o[j] = f2b(Wi[((size_t)e * DIN + kb + j) * DHID + n]);
        *(ushort8*)(wiP + (size_t)idx * 8) = o;
    } else {
        int i2 = idx - NWI;
        if (i2 >= NWO) return;
        int L = i2 & 63; int r = i2 >> 6;
        int ks = r & 15; r >>= 4;
        int t2 = r & 7; int e = r >> 3;
        int n = t2 * 16 + (L & 15);
        int kb = ks * 32 + ((L >> 4) & 3) * 8;
        ushort8 o;
        #pragma unroll
        for (int j = 0; j < 8; ++j)
            o[j] = f2b(Wo[((size_t)e * DHID + kb + j) * DMODEL + n]);
        *(ushort8*)(woP + (size_t)i2 * 8) = o;
    }
}

// async-stage one SUPER-step (64 hidden units) of weights: 36 KB = 2304
// granules of 16B = exactly 9 per thread (uniform, no tail).
// granules: [0,1280) Wi contiguous at ss*20KB; [1280,2304) Wo:
// n = g2>>7, kl = (g2>>6)&1, row = g2&63 -> src (n*16 + 2*ss+kl) region.
__device__ __forceinline__ void stage_super(
    const ushort_t* __restrict__ wiPe, const ushort_t* __restrict__ woPe,
    ushort_t* dstBuf, int ss, int tid)
{
    #pragma unroll
    for (int it = 0; it < 9; ++it) {
        int g = it * 256 + tid;
        const ushort_t* src;
        if (g < 1280) {
            src = wiPe + (size_t)ss * 10240 + (size_t)g * 8;
        } else {
            int g2 = g - 1280;
            int n = g2 >> 7, kl = (g2 >> 6) & 1, row = g2 & 63;
            src = woPe + ((size_t)((n * 16 + 2 * ss + kl) * 64 + row)) * 8;
        }
        __builtin_amdgcn_global_load_lds((gu32p)(const void*)src,
                                         (lu32p)(void*)(dstBuf + g * 8), 16, 0, 0);
    }
}

// x = concat(hidden[t], emb[bi]); 8 consecutive floats at col c0 (8-aligned)
__device__ __forceinline__ bf16x8 load_x8(const float* __restrict__ hidden,
                                          const float* __restrict__ emb,
                                          int t, int bi, int c0) {
    if (t < 0) return (bf16x8)0;
    const float* src = (c0 < DMODEL) ? (hidden + (size_t)t * DMODEL + c0)
                                     : (emb + (size_t)bi * BEH + (c0 - DMODEL));
    f32x4 p0 = *(const f32x4*)src;
    f32x4 p1 = *(const f32x4*)(src + 4);
    uint32_t d0 = pk2(p0[0], p0[1]), d1 = pk2(p0[2], p0[3]);
    uint32_t d2 = pk2(p1[0], p1[1]), d3 = pk2(p1[2], p1[3]);
    return __builtin_bit_cast(bf16x8, (uint4){d0, d1, d2, d3});
}

// ---------------- Phase C: per-expert fused MLP ----------------
// block = 128 tokens, 4 waves, wave owns 32 tokens (2 token-tiles).
// R0 topology (global_load_lds staging + __syncthreads 2-phase) with BK=64:
// 8 super-steps x 36 KB instead of 16 steps x 18 KB -- half the barrier/
// drain events, each amortized over 2x compute. Per-wave dataflow identical.
__global__ __launch_bounds__(256, 2) void expert_gemm(
    const float* __restrict__ hidden, const int* __restrict__ bindex,
    const int* __restrict__ lists, const int* __restrict__ counts,
    const ushort_t* __restrict__ wiP, const ushort_t* __restrict__ woP,
    const float* __restrict__ emb, float* __restrict__ out)
{
    int e = blockIdx.y;
    int tile = blockIdx.x;
    int count = counts[e]; if (count > CAP) count = CAP;
    int base = tile * MT;
    if (base >= count) return;
    int mvalid = count - base; if (mvalid > MT) mvalid = MT;

    __shared__ ushort_t wbuf[2][SUPER_SHORTS];   // 72 KB

    int tid = threadIdx.x;
    int lane = tid & 63;
    int w = tid >> 6;
    int l15 = lane & 15;
    int quad = lane >> 4;

    const int* listE = lists + (size_t)e * CAP + base;
    const ushort_t* wiPe = wiP + (size_t)e * 32 * 5 * 64 * 8;
    const ushort_t* woPe = woP + (size_t)e * 8 * 16 * 64 * 8;

    // kick off super-step-0 staging before the x gather (overlap L2 latency)
    stage_super(wiPe, woPe, wbuf[0], 0, tid);

    // ---- x B-fragments in registers: lane holds x[k=s*32+quad*8+j][tok=base+tt*16+l15]
    bf16x8 xf[2][5];
    int tok[2], bi[2];
    #pragma unroll
    for (int tt = 0; tt < 2; ++tt) {
        int row = w * 32 + tt * 16 + l15;
        tok[tt] = -1; bi[tt] = 0;
        if (row < mvalid) { tok[tt] = listE[row]; bi[tt] = bindex[tok[tt]]; }
    }
    #pragma unroll
    for (int s = 0; s < 5; ++s) {
        int c0 = s * 32 + quad * 8;
        xf[0][s] = load_x8(hidden, emb, tok[0], bi[0], c0);
        xf[1][s] = load_x8(hidden, emb, tok[1], bi[1], c0);
    }

    int srcA = (quad & 1) * 32 + l15;   // shuffle sources for h layout transform
    int srcB = srcA + 16;
    int selM1 = quad >> 1;

    f32x4 yacc[2][8] = {};

    #pragma unroll 2
    for (int ss = 0; ss < 8; ++ss) {            // 8 super-steps of 64 hidden units
        int cur = ss & 1;
        __syncthreads();                        // wbuf[cur] staged (drains vmcnt)
        if (ss + 1 < 8)
            stage_super(wiPe, woPe, wbuf[cur ^ 1], ss + 1, tid);

        #pragma unroll
        for (int kl = 0; kl < 2; ++kl) {        // two 32-unit sub-steps
            const ushort_t* wiS = wbuf[cur] + kl * 5120;   // [2 tiles][5 s][64][8]
            const ushort_t* woS = wbuf[cur] + WO_BASE;     // [8 n][2 kl][64][8]

            // GEMM1^T: hT[32 hid x 32 tok] = Wi-tiles @ x
            f32x4 hacc[2][2] = {};
            #pragma unroll
            for (int s = 0; s < 5; ++s) {
                bf16x8 a0 = *(const bf16x8*)&wiS[(0 * 5 + s) * 512 + lane * 8];
                bf16x8 a1 = *(const bf16x8*)&wiS[(1 * 5 + s) * 512 + lane * 8];
                #pragma unroll
                for (int tt = 0; tt < 2; ++tt) {
                    hacc[0][tt] = __builtin_amdgcn_mfma_f32_16x16x32_bf16(a0, xf[tt][s], hacc[0][tt], 0, 0, 0);
                    hacc[1][tt] = __builtin_amdgcn_mfma_f32_16x16x32_bf16(a1, xf[tt][s], hacc[1][tt], 0, 0, 0);
                }
            }
            // relu + pack + shuffle-transpose -> GEMM2 A-frags
            bf16x8 afrag[2];
            #pragma unroll
            for (int tt = 0; tt < 2; ++tt) {
                f32x4 h0 = hacc[0][tt], h1 = hacc[1][tt];
                #pragma unroll
                for (int r = 0; r < 4; ++r) {
                    h0[r] = h0[r] > 0.f ? h0[r] : 0.f;
                    h1[r] = h1[r] > 0.f ? h1[r] : 0.f;
                }
                uint32_t p00 = pk2(h0[0], h0[1]), p01 = pk2(h0[2], h0[3]);
                uint32_t p10 = pk2(h1[0], h1[1]), p11 = pk2(h1[2], h1[3]);
                uint32_t a00 = (uint32_t)__shfl((int)p00, srcA);
                uint32_t a01 = (uint32_t)__shfl((int)p01, srcA);
                uint32_t a02 = (uint32_t)__shfl((int)p00, srcB);
                uint32_t a03 = (uint32_t)__shfl((int)p01, srcB);
                uint32_t a10 = (uint32_t)__shfl((int)p10, srcA);
                uint32_t a11 = (uint32_t)__shfl((int)p11, srcA);
                uint32_t a12 = (uint32_t)__shfl((int)p10, srcB);
                uint32_t a13 = (uint32_t)__shfl((int)p11, srcB);
                uint4 dv = { selM1 ? a10 : a00, selM1 ? a11 : a01,
                             selM1 ? a12 : a02, selM1 ? a13 : a03 };
                afrag[tt] = __builtin_bit_cast(bf16x8, dv);
            }
            // GEMM2: b-frag loaded once per n (tt-invariant), 2 MFMAs per load
            #pragma unroll
            for (int n = 0; n < 8; ++n) {
                bf16x8 b = *(const bf16x8*)&woS[((n * 2 + kl) * 64 + lane) * 8];
                yacc[0][n] = __builtin_amdgcn_mfma_f32_16x16x32_bf16(afrag[0], b, yacc[0][n], 0, 0, 0);
                yacc[1][n] = __builtin_amdgcn_mfma_f32_16x16x32_bf16(afrag[1], b, yacc[1][n], 0, 0, 0);
            }
        }
    }

    // epilogue: yacc C-layout -> out[token][dmodel]
    #pragma unroll
    for (int tt = 0; tt < 2; ++tt)
        #pragma unroll
        for (int r = 0; r < 4; ++r) {
            int row = w * 32 + tt * 16 + quad * 4 + r;
            if (row < mvalid) {
                int t = listE[row];
                float* dst = out + (size_t)t * DMODEL + l15;
                #pragma unroll
                for (int n = 0; n < 8; ++n)
                    dst[n * 16] = yacc[tt][n][r];
            }
        }
}

extern "C" void kernel_launch(void* const* d_in, const int* in_sizes, int n_in,
                              void* d_out, int out_size, void* d_ws, size_t ws_size,
                              hipStream_t stream) {
    const float* hidden = (const float*)d_in[0];
    const int*   pos    = (const int*)d_in[1];
    const int*   beh    = (const int*)d_in[2];
    const float* Wi     = (const float*)d_in[3];
    const float* Wo     = (const float*)d_in[4];
    const float* emb    = (const float*)d_in[5];

    char* ws = (char*)d_ws;
    int* counts   = (int*)(ws + OFF_COUNTS);
    int* lists    = (int*)(ws + OFF_LISTS);
    ushort_t* wiP = (ushort_t*)(ws + OFF_WIP);
    ushort_t* woP = (ushort_t*)(ws + OFF_WOP);

    hipMemsetAsync(counts, 0, NEXP * sizeof(int), stream);
    prep_kernel<<<SCATTER_BLOCKS + PACK_BLOCKS, 256, 0, stream>>>(pos, counts, lists, Wi, Wo, wiP, woP);
    expert_gemm<<<dim3(TILES, NEXP), 256, 0, stream>>>(
        hidden, beh, lists, counts, wiP, woP, emb, (float*)d_out);
}